// Round 4
// baseline (692.739 us; speedup 1.0000x reference)
//
#include <hip/hip_runtime.h>

#define D_MODEL 1024
#define D_FF    4096
#define N_HEADS 16
#define DK      64
#define BATCH   4
#define SEQ     2048
#define M_TOT   (BATCH*SEQ)   // 8192

typedef unsigned short ushort_t;
typedef __attribute__((ext_vector_type(8)))  short  short8;
typedef __attribute__((ext_vector_type(4)))  float  floatx4;
typedef __attribute__((ext_vector_type(16))) float  floatx16;

__device__ __forceinline__ float bf2f(ushort_t s) {
    return __uint_as_float(((unsigned int)s) << 16);
}
__device__ __forceinline__ ushort_t f2bf(float f) {
    unsigned int u = __float_as_uint(f);
    u += 0x7fff + ((u >> 16) & 1);   // round-to-nearest-even
    return (ushort_t)(u >> 16);
}
// async global->LDS, 16B per lane; LDS dest = wave-uniform base + lane*16
__device__ __forceinline__ void gll16(const void* g, void* l) {
    __builtin_amdgcn_global_load_lds(
        (const __attribute__((address_space(1))) void*)g,
        (__attribute__((address_space(3))) void*)l,
        16, 0, 0);
}

#if __has_builtin(__builtin_amdgcn_exp2f)
#define EXP2(x) __builtin_amdgcn_exp2f(x)
#else
#define EXP2(x) __expf((x) * 0.69314718055994531f)
#endif
#define L2E 1.4426950408889634f

// ---------------------------------------------------------------------------
// dtype detector (validated R5/R6)
// ---------------------------------------------------------------------------
__global__ void detect_dtype(const ushort_t* __restrict__ x, int* __restrict__ flag)
{
    const int t = threadIdx.x;
    int cnt = 0;
    for (int i = t; i < 512; i += 64) {
        ushort_t e = x[2 * i] & 0x7F80;
        cnt += (e >= 0x3800 && e <= 0x4380) ? 1 : 0;
    }
    for (int off = 32; off > 0; off >>= 1) cnt += __shfl_down(cnt, off, 64);
    if (t == 0) { flag[0] = (cnt >= 256) ? 1 : 0; flag[1] = 0; }
}

// ---------------------------------------------------------------------------
// fused param converter: all 10 small fp32/bf16 vectors -> one packed block.
// packed layout (floats): 0 bqkv(3072, q pre-scaled 1/8) | 3072 bo |
// 4096 b1(4096) | 8192 b2 | 9216 a1 | 10240 be1 | 11264 a2 | 12288 be2
// ---------------------------------------------------------------------------
__global__ void cvt_params(
    const void* bq, const void* bk, const void* bv, const void* bo,
    const void* b1, const void* b2, const void* a1, const void* be1,
    const void* a2, const void* be2, float* __restrict__ dst,
    const int* __restrict__ flag)
{
    const int e = blockIdx.x * 256 + threadIdx.x;   // 0..13311
    const int seg = e >> 10;                        // 0..12
    const void* srcs[13] = {bq, bk, bv, bo, b1, b1, b1, b1, b2, a1, be1, a2, be2};
    const int   base[13] = {0, 1024, 2048, 3072, 4096, 4096, 4096, 4096,
                            8192, 9216, 10240, 11264, 12288};
    const void* s = srcs[seg];
    const int off = e - base[seg];
    const float scale = (seg == 0) ? 0.125f : 1.f;
    float v = (*flag) ? bf2f(((const ushort_t*)s)[off]) : ((const float*)s)[off];
    dst[e] = v * scale;
}

// ---------------------------------------------------------------------------
// weight transpose (+optional scale): in[K][N] -> out[N][K] bf16
// ---------------------------------------------------------------------------
__device__ __forceinline__ void transpose_body(
    const void* __restrict__ in, ushort_t* __restrict__ out, int K, int N,
    float scale, int fl, ushort_t* tile, int n0, int k0)
{
    const int t = threadIdx.x, sr = t >> 2, sc = (t & 3) * 16;
    const long g = (long)(k0 + sr) * N + n0 + sc;
    ushort_t cv[16];
    if (fl) {
        const ushort_t* p = (const ushort_t*)in;
        #pragma unroll
        for (int j = 0; j < 16; j++) cv[j] = f2bf(bf2f(p[g + j]) * scale);
    } else {
        const float* p = (const float*)in;
        #pragma unroll
        for (int j = 0; j < 16; j += 4) {
            float4 fv = *(const float4*)&p[g + j];
            cv[j] = f2bf(fv.x * scale); cv[j+1] = f2bf(fv.y * scale);
            cv[j+2] = f2bf(fv.z * scale); cv[j+3] = f2bf(fv.w * scale);
        }
    }
    #pragma unroll
    for (int j = 0; j < 16; j++) tile[sr * 72 + sc + j] = cv[j];
    __syncthreads();
    __attribute__((aligned(16))) ushort_t tmp[16];
    #pragma unroll
    for (int j = 0; j < 16; j++) tmp[j] = tile[(sc + j) * 72 + sr];
    const long go = (long)(n0 + sr) * K + k0 + sc;
    *(int4*)&out[go]     = *(const int4*)&tmp[0];
    *(int4*)&out[go + 8] = *(const int4*)&tmp[8];
}

__global__ __launch_bounds__(256) void transpose_to_bf16(
    const void* __restrict__ in, ushort_t* __restrict__ out, int K, int N,
    float scale, const int* __restrict__ flag)
{
    __shared__ ushort_t tile[64 * 72];
    transpose_body(in, out, K, N, scale, *flag, tile,
                   blockIdx.x * 64, blockIdx.y * 64);
}

// batched square transpose for wq/wk/wv/wo (dsts contiguous in ws)
__global__ __launch_bounds__(256) void transpose_qkvo(
    const void* __restrict__ wq, const void* __restrict__ wk,
    const void* __restrict__ wv, const void* __restrict__ wo,
    ushort_t* __restrict__ out, const int* __restrict__ flag)
{
    __shared__ ushort_t tile[64 * 72];
    const int z = blockIdx.z;
    const void* in = (z == 0) ? wq : (z == 1) ? wk : (z == 2) ? wv : wo;
    transpose_body(in, out + (long)z * 1024 * 1024, 1024, 1024,
                   (z == 0) ? 0.125f : 1.f, *flag, tile,
                   blockIdx.x * 64, blockIdx.y * 64);
}

// ---------------------------------------------------------------------------
// Tensor1DNorm (validated)
// ---------------------------------------------------------------------------
__global__ __launch_bounds__(256) void ln_kernel(
    const void* __restrict__ xraw, const float* __restrict__ alpha,
    const float* __restrict__ beta, ushort_t* __restrict__ out,
    const int* __restrict__ flag)
{
    __shared__ float red[8];
    __shared__ float stats[2];
    const int row = blockIdx.x, t = threadIdx.x;
    const long idx = (long)row * D_MODEL + t * 4;
    float v0, v1, v2, v3;
    if (*flag) {
        ushort4 u = *(const ushort4*)&((const ushort_t*)xraw)[idx];
        v0 = bf2f(u.x); v1 = bf2f(u.y); v2 = bf2f(u.z); v3 = bf2f(u.w);
    } else {
        float4 fv = *(const float4*)&((const float*)xraw)[idx];
        v0 = fv.x; v1 = fv.y; v2 = fv.z; v3 = fv.w;
    }
    float s  = v0 + v1 + v2 + v3;
    float s2 = v0 * v0 + v1 * v1 + v2 * v2 + v3 * v3;
    for (int off = 32; off > 0; off >>= 1) {
        s  += __shfl_down(s,  off, 64);
        s2 += __shfl_down(s2, off, 64);
    }
    const int w = t >> 6, lane = t & 63;
    if (lane == 0) { red[w] = s; red[4 + w] = s2; }
    __syncthreads();
    if (t == 0) {
        float S  = red[0] + red[1] + red[2] + red[3];
        float S2 = red[4] + red[5] + red[6] + red[7];
        float mean = S / D_MODEL;
        float var  = fmaxf((S2 - mean * S) / (D_MODEL - 1), 0.f);
        stats[0] = mean;
        stats[1] = 1.f / (sqrtf(var) + 1e-6f);
    }
    __syncthreads();
    const float mean = stats[0], inv = stats[1];
    float vv[4] = {v0, v1, v2, v3};
    ushort4 o;
    ushort_t* op = (ushort_t*)&o;
    #pragma unroll
    for (int j = 0; j < 4; j++)
        op[j] = f2bf(alpha[t * 4 + j] * (vv[j] - mean) * inv + beta[t * 4 + j]);
    *(ushort4*)&out[idx] = o;
}

// ---------------------------------------------------------------------------
// GEMM core: 128x128 tile, BK=64, gll16 staging + XOR swizzle (R3-validated),
// now with 32x32x16 MFMA (+15% pipe efficiency, half the MFMA instructions)
// and bijective XCD swizzle (contiguous tile chunks per XCD for L2 locality;
// all grids are %8==0).
// Per wave: 64x64 output = 2x2 frags of 32x32 (floatx16 each).
// A/B fragment: lane holds row=(lane&31), k=(lane>>5)*8 + e (8 bf16, b128).
// D layout (m74/m101): col=lane&31 (B-side), row=(r&3)+8*(r>>2)+4*(lane>>5).
// ---------------------------------------------------------------------------
#define GEMM_PROLOG()                                                         \
    __shared__ ushort_t As[128 * 64];                                         \
    __shared__ ushort_t Bs[128 * 64];                                         \
    const int nwg = gridDim.x * gridDim.y;                                    \
    const int bid = blockIdx.y * gridDim.x + blockIdx.x;                      \
    const int wg2 = (bid & 7) * (nwg >> 3) + (bid >> 3);                      \
    const int m0 = (wg2 % gridDim.x) * 128, n0 = (wg2 / gridDim.x) * 128;     \
    const int t = threadIdx.x;                                                \
    const int w = t >> 6, lane = t & 63;                                      \
    const int l31 = lane & 31, hi = lane >> 5;                                \
    const int wm = (w >> 1) * 64, wn = (w & 1) * 64;                          \
    const int srow = lane >> 3;                    /* staging row-in-8 */     \
    const int scol = 8 * ((lane & 7) ^ (srow & 7)); /* pre-swizzled col */    \
    const int rswz = (lane & 7) * 8;               /* read-side XOR */        \
    floatx16 acc[2][2] = {};

#define GEMM_KLOOP(Abase, LDA, Bbase, LDB, KLEN)                              \
    {                                                                         \
    const ushort_t* gA = (Abase) + (long)(m0 + w * 32 + srow) * (LDA) + scol; \
    const ushort_t* gB = (Bbase) + (long)(n0 + w * 32 + srow) * (LDB) + scol; \
    for (int k0 = 0; k0 < (KLEN); k0 += 64) {                                 \
        _Pragma("unroll")                                                     \
        for (int c = 0; c < 4; c++) {                                         \
            gll16(gA + k0 + (long)(c * 8) * (LDA), &As[(w * 32 + c * 8) * 64]);\
            gll16(gB + k0 + (long)(c * 8) * (LDB), &Bs[(w * 32 + c * 8) * 64]);\
        }                                                                     \
        __syncthreads();                                                      \
        _Pragma("unroll")                                                     \
        for (int kk = 0; kk < 2; kk++) {                                      \
            short8 af[2][2], bf[2][2];                                        \
            _Pragma("unroll")                                                 \
            for (int i = 0; i < 2; i++) {                                     \
                _Pragma("unroll")                                             \
                for (int kh = 0; kh < 2; kh++) {                              \
                    const int kc = (kk * 32 + kh * 16 + hi * 8) ^ rswz;       \
                    af[i][kh] = *(const short8*)&As[(wm + i * 32 + l31) * 64 + kc]; \
                    bf[i][kh] = *(const short8*)&Bs[(wn + i * 32 + l31) * 64 + kc]; \
                }                                                             \
            }                                                                 \
            _Pragma("unroll")                                                 \
            for (int kh = 0; kh < 2; kh++) {                                  \
                _Pragma("unroll")                                             \
                for (int i = 0; i < 2; i++) {                                 \
                    _Pragma("unroll")                                         \
                    for (int j = 0; j < 2; j++)                               \
                        acc[i][j] = __builtin_amdgcn_mfma_f32_32x32x16_bf16(  \
                            af[i][kh], bf[j][kh], acc[i][j], 0, 0, 0);        \
                }                                                             \
            }                                                                 \
        }                                                                     \
        __syncthreads();                                                      \
    }                                                                         \
    }

// Fused QKV: BT = wqkvT [3072][1024]; epilogue routes per 1024-segment.
// seg0 -> qb [M][1024]; seg1 -> kb; seg2 -> vt [B][H][DK][S].
__global__ __launch_bounds__(256) void gemm_qkv(
    const ushort_t* __restrict__ A, const ushort_t* __restrict__ BT,
    const float* __restrict__ bias, ushort_t* __restrict__ qb,
    ushort_t* __restrict__ kb, ushort_t* __restrict__ vtb, int M, int K)
{
    GEMM_PROLOG();
    GEMM_KLOOP(A, K, BT, K, K);
    const int nbase = n0 + wn;          // multiple of 64; wave-uniform segment
    const int seg = nbase >> 10;
    #pragma unroll
    for (int j = 0; j < 2; j++) {
        const int ng = nbase + j * 32 + l31;
        const float bv = bias[ng];
        const int nl = ng & 1023;
        #pragma unroll
        for (int i = 0; i < 2; i++) {
            const int mb_ = m0 + wm + i * 32 + 4 * hi;
            if (seg == 2) {
                #pragma unroll
                for (int rg = 0; rg < 4; rg++) {
                    ushort4 pv;
                    #pragma unroll
                    for (int rr = 0; rr < 4; rr++)
                        ((ushort_t*)&pv)[rr] = f2bf(acc[i][j][rg * 4 + rr] + bv);
                    const int m = mb_ + 8 * rg;
                    const long idx = ((long)(m >> 11) * 1024 + nl) * 2048 + (m & 2047);
                    *(ushort4*)&vtb[idx] = pv;
                }
            } else {
                ushort_t* dst = seg ? kb : qb;
                #pragma unroll
                for (int rg = 0; rg < 4; rg++) {
                    #pragma unroll
                    for (int rr = 0; rr < 4; rr++)
                        dst[(long)(mb_ + 8 * rg + rr) * 1024 + nl] =
                            f2bf(acc[i][j][rg * 4 + rr] + bv);
                }
            }
        }
    }
}

// O-proj: trunk fp32 = A @ BT^T + bias + raw-x residual (flag-typed)
__global__ __launch_bounds__(256) void gemm_bias_res_trunk(
    const ushort_t* __restrict__ A, const ushort_t* __restrict__ BT,
    const float* __restrict__ bias, const void* __restrict__ res,
    float* __restrict__ C, int M, int N, int K, const int* __restrict__ flag)
{
    GEMM_PROLOG();
    const int fl = *flag;
    GEMM_KLOOP(A, K, BT, K, K);
    #pragma unroll
    for (int j = 0; j < 2; j++) {
        const int n = n0 + wn + j * 32 + l31;
        const float bv = bias[n];
        #pragma unroll
        for (int i = 0; i < 2; i++) {
            const int mb_ = m0 + wm + i * 32 + 4 * hi;
            #pragma unroll
            for (int rg = 0; rg < 4; rg++) {
                #pragma unroll
                for (int rr = 0; rr < 4; rr++) {
                    const long idx = (long)(mb_ + 8 * rg + rr) * N + n;
                    const float rv = fl ? bf2f(((const ushort_t*)res)[idx])
                                        : ((const float*)res)[idx];
                    C[idx] = acc[i][j][rg * 4 + rr] + bv + rv;
                }
            }
        }
    }
}

// FF1 slice: C[M][Nc] bf16 = relu(A @ BT[noff..]^T + bias[noff..])
__global__ __launch_bounds__(256) void gemm_relu_slice(
    const ushort_t* __restrict__ A, const ushort_t* __restrict__ BT,
    const float* __restrict__ bias, ushort_t* __restrict__ C,
    int M, int Nc, int K, int noff)
{
    GEMM_PROLOG();
    const ushort_t* BTo = BT + (long)noff * K;
    GEMM_KLOOP(A, K, BTo, K, K);
    #pragma unroll
    for (int j = 0; j < 2; j++) {
        const int n = n0 + wn + j * 32 + l31;
        const float bv = bias[noff + n];
        #pragma unroll
        for (int i = 0; i < 2; i++) {
            const int mb_ = m0 + wm + i * 32 + 4 * hi;
            #pragma unroll
            for (int rg = 0; rg < 4; rg++) {
                #pragma unroll
                for (int rr = 0; rr < 4; rr++)
                    C[(long)(mb_ + 8 * rg + rr) * Nc + n] =
                        f2bf(fmaxf(acc[i][j][rg * 4 + rr] + bv, 0.f));
            }
        }
    }
}

// FF2 slice accumulate into fp32 trunk (pass0: += bias; trunk holds residual)
__global__ __launch_bounds__(256) void gemm_acc_slice(
    const ushort_t* __restrict__ A, const ushort_t* __restrict__ BT,
    const float* __restrict__ bias, float* __restrict__ C,
    int M, int N, int Kc, int koff, int Kfull, int pass0)
{
    GEMM_PROLOG();
    const ushort_t* BTo = BT + koff;
    GEMM_KLOOP(A, Kc, BTo, Kfull, Kc);
    #pragma unroll
    for (int j = 0; j < 2; j++) {
        const int n = n0 + wn + j * 32 + l31;
        const float bv = pass0 ? bias[n] : 0.f;
        #pragma unroll
        for (int i = 0; i < 2; i++) {
            const int mb_ = m0 + wm + i * 32 + 4 * hi;
            #pragma unroll
            for (int rg = 0; rg < 4; rg++) {
                #pragma unroll
                for (int rr = 0; rr < 4; rr++) {
                    const long idx = (long)(mb_ + 8 * rg + rr) * N + n;
                    C[idx] = C[idx] + bv + acc[i][j][rg * 4 + rr];
                }
            }
        }
    }
}

// FF2 final slice: out (per flag dtype) = Cin + A @ BTslice^T
__global__ __launch_bounds__(256) void gemm_acc_final(
    const ushort_t* __restrict__ A, const ushort_t* __restrict__ BT,
    const float* __restrict__ Cin, void* __restrict__ out,
    int M, int N, int Kc, int koff, int Kfull, const int* __restrict__ flag)
{
    GEMM_PROLOG();
    const int fl = *flag;
    const ushort_t* BTo = BT + koff;
    GEMM_KLOOP(A, Kc, BTo, Kfull, Kc);
    #pragma unroll
    for (int j = 0; j < 2; j++) {
        const int n = n0 + wn + j * 32 + l31;
        #pragma unroll
        for (int i = 0; i < 2; i++) {
            const int mb_ = m0 + wm + i * 32 + 4 * hi;
            #pragma unroll
            for (int rg = 0; rg < 4; rg++) {
                #pragma unroll
                for (int rr = 0; rr < 4; rr++) {
                    const long idx = (long)(mb_ + 8 * rg + rr) * N + n;
                    const float v = Cin[idx] + acc[i][j][rg * 4 + rr];
                    if (fl) ((ushort_t*)out)[idx] = f2bf(v);
                    else    ((float*)out)[idx] = v;
                }
            }
        }
    }
}

__global__ __launch_bounds__(256) void finalize_out(
    const float* __restrict__ trunk, void* __restrict__ out,
    const int* __restrict__ flag)
{
    const long i = ((long)blockIdx.x * 256 + threadIdx.x) * 4;
    float4 tv = *(const float4*)&trunk[i];
    if (*flag) {
        ushort4 o = { f2bf(tv.x), f2bf(tv.y), f2bf(tv.z), f2bf(tv.w) };
        *(ushort4*)&((ushort_t*)out)[i] = o;
    } else {
        *(float4*)&((float*)out)[i] = tv;
    }
}

// ---------------------------------------------------------------------------
// Flash attention v5 (R2-validated): QBLK=128, fixed-max softmax, ones-MFMA
// row-sum, reg-prefetch staging, Q hoisted, Ps aliases Q staging region.
// ---------------------------------------------------------------------------
__global__ __launch_bounds__(256) void attn_kernel(
    const ushort_t* __restrict__ q, const ushort_t* __restrict__ k,
    const ushort_t* __restrict__ vt, const int* __restrict__ mask,
    ushort_t* __restrict__ out)
{
    __shared__ ushort_t Ks[64 * 72];
    __shared__ ushort_t Vs[64 * 72];
    __shared__ ushort_t Ps[128 * 72];   // Q staging first, then P tile
    __shared__ float MbL[64];
    const int qt = blockIdx.x, bh = blockIdx.y;
    const int b = bh >> 4, h = bh & 15;
    const int t = threadIdx.x, w = t >> 6, lane = t & 63;
    const int quad = lane >> 4, l15 = lane & 15;
    const int sr = t >> 2, sc = (t & 3) * 16;
    const int q0 = qt * 128;
    const long rowbase = (long)b * SEQ * D_MODEL + (long)h * DK;
    const long vtbase  = ((long)(b * 16 + h) * DK) * SEQ;

    // ---- stage Q 128x64 (wave-private rows: wave w stages rows 32w..32w+31)
    {
        const int qr = t >> 1, qc = (t & 1) * 32;
        const long g = rowbase + (long)(q0 + qr) * D_MODEL + qc;
        *(int4*)&Ps[qr * 72 + qc]      = *(const int4*)&q[g];
        *(int4*)&Ps[qr * 72 + qc + 8]  = *(const int4*)&q[g + 8];
        *(int4*)&Ps[qr * 72 + qc + 16] = *(const int4*)&q[g + 16];
        *(int4*)&Ps[qr * 72 + qc + 24] = *(const int4*)&q[g + 24];
    }
    // hoist loop-invariant Q fragments (same-wave LDS: no barrier needed)
    short8 bq[2][2];
    #pragma unroll
    for (int qg = 0; qg < 2; qg++)
        #pragma unroll
        for (int ks = 0; ks < 2; ks++)
            bq[qg][ks] = *(const short8*)&Ps[(w * 32 + qg * 16 + l15) * 72 + ks * 32 + quad * 8];

    short8 bones;
    #pragma unroll
    for (int i = 0; i < 8; i++) bones[i] = (short)0x3F80;   // bf16 1.0

    floatx4 o[2][4] = {};
    floatx4 l4[2] = {};    // row-sum accumulators (P·1)

    // ---- prefetch K/V tile 0 + mask into registers
    int4 kra, krb, vra, vrb;
    int  mreg = 0;
    {
        const long gk = rowbase + (long)sr * D_MODEL + sc;
        kra = *(const int4*)&k[gk]; krb = *(const int4*)&k[gk + 8];
        const long gv = vtbase + (long)sr * SEQ + sc;
        vra = *(const int4*)&vt[gv]; vrb = *(const int4*)&vt[gv + 8];
        if (t < 64) mreg = mask[b * SEQ + t];
    }

    for (int kt = 0; kt < SEQ / 64; kt++) {
        __syncthreads();     // previous iteration's readers done
        *(int4*)&Ks[sr * 72 + sc]     = kra;
        *(int4*)&Ks[sr * 72 + sc + 8] = krb;
        *(int4*)&Vs[sr * 72 + sc]     = vra;
        *(int4*)&Vs[sr * 72 + sc + 8] = vrb;
        if (t < 64) MbL[t] = (mreg == 0) ? -1.0e9f : -44.0f;
        __syncthreads();
        if (kt + 1 < SEQ / 64) {   // issue next-tile loads; compute hides them
            const long gk = rowbase + (long)((kt + 1) * 64 + sr) * D_MODEL + sc;
            kra = *(const int4*)&k[gk]; krb = *(const int4*)&k[gk + 8];
            const long gv = vtbase + (long)sr * SEQ + (kt + 1) * 64 + sc;
            vra = *(const int4*)&vt[gv]; vrb = *(const int4*)&vt[gv + 8];
            if (t < 64) mreg = mask[b * SEQ + (kt + 1) * 64 + t];
        }

        // S^T = K·Q^T  (q pre-scaled by 1/8); each ak feeds 2 q-groups
        floatx4 s[4][2] = {};
        __builtin_amdgcn_s_setprio(1);
        #pragma unroll
        for (int nt = 0; nt < 4; nt++) {
            short8 ak0 = *(const short8*)&Ks[(nt * 16 + l15) * 72 + quad * 8];
            s[nt][0] = __builtin_amdgcn_mfma_f32_16x16x32_bf16(ak0, bq[0][0], s[nt][0], 0, 0, 0);
            s[nt][1] = __builtin_amdgcn_mfma_f32_16x16x32_bf16(ak0, bq[1][0], s[nt][1], 0, 0, 0);
            short8 ak1 = *(const short8*)&Ks[(nt * 16 + l15) * 72 + 32 + quad * 8];
            s[nt][0] = __builtin_amdgcn_mfma_f32_16x16x32_bf16(ak1, bq[0][1], s[nt][0], 0, 0, 0);
            s[nt][1] = __builtin_amdgcn_mfma_f32_16x16x32_bf16(ak1, bq[1][1], s[nt][1], 0, 0, 0);
        }
        __builtin_amdgcn_s_setprio(0);

        // p = exp2(s*L2E - 44); masked cols -> -1e9 -> exactly 0.
        // P packed to bf16 by truncation via v_perm (2 values/op).
        #pragma unroll
        for (int qg = 0; qg < 2; qg++) {
            #pragma unroll
            for (int nt = 0; nt < 4; nt++) {
                float4 mb4 = *(const float4*)&MbL[nt * 16 + quad * 4];
                float p[4];
                #pragma unroll
                for (int r = 0; r < 4; r++)
                    p[r] = EXP2(fmaf(s[nt][qg][r], L2E, ((const float*)&mb4)[r]));
                uint2 pk;
                pk.x = __builtin_amdgcn_perm(__float_as_uint(p[1]), __float_as_uint(p[0]), 0x07060302u);
                pk.y = __builtin_amdgcn_perm(__float_as_uint(p[3]), __float_as_uint(p[2]), 0x07060302u);
                *(uint2*)&Ps[(w * 32 + qg * 16 + l15) * 72 + nt * 16 + quad * 4] = pk;
            }
        }

        // O += P·V ; l4 += P·1  (Ps rows wave-private: no barrier needed);
        // each bv feeds 2 q-groups.
        __builtin_amdgcn_s_setprio(1);
        #pragma unroll
        for (int ks = 0; ks < 2; ks++) {
            short8 ap0 = *(const short8*)&Ps[(w * 32 + l15) * 72 + ks * 32 + quad * 8];
            short8 ap1 = *(const short8*)&Ps[(w * 32 + 16 + l15) * 72 + ks * 32 + quad * 8];
            #pragma unroll
            for (int j = 0; j < 4; j++) {
                short8 bv = *(const short8*)&Vs[(j * 16 + l15) * 72 + ks * 32 + quad * 8];
                o[0][j] = __builtin_amdgcn_mfma_f32_16x16x32_bf16(ap0, bv, o[0][j], 0, 0, 0);
                o[1][j] = __builtin_amdgcn_mfma_f32_16x16x32_bf16(ap1, bv, o[1][j], 0, 0, 0);
            }
            l4[0] = __builtin_amdgcn_mfma_f32_16x16x32_bf16(ap0, bones, l4[0], 0, 0, 0);
            l4[1] = __builtin_amdgcn_mfma_f32_16x16x32_bf16(ap1, bones, l4[1], 0, 0, 0);
        }
        __builtin_amdgcn_s_setprio(0);
    }
    // l4[qg][r] = row-sum for q-row (w*32 + qg*16 + quad*4 + r)
    #pragma unroll
    for (int qg = 0; qg < 2; qg++) {
        float inv[4];
        #pragma unroll
        for (int r = 0; r < 4; r++) inv[r] = 1.f / l4[qg][r];
        #pragma unroll
        for (int j = 0; j < 4; j++) {
            const int d = j * 16 + l15;
            #pragma unroll
            for (int r = 0; r < 4; r++) {
                const int row = q0 + w * 32 + qg * 16 + quad * 4 + r;
                out[rowbase + (long)row * D_MODEL + d] = f2bf(o[qg][j][r] * inv[r]);
            }
        }
    }
}

// ---------------------------------------------------------------------------
// Launch. Common: 0-6 wqkvT, 6-8 woT, 8-16 w1T, 16-24 w2T, 24-25 params,
// 25-41 lnbuf/attnb, 41-57 qb, 57-73 kb, 73-89 vtb.
// Path A (ws>=121MB): trunk fp32 57-89, ln2buf 41-57, halfbuf 89-121, FF halves.
// Path B: R6-proven quarters (trunk 41-73, ln2buf 73-89, halfbuf 25-41).
// ---------------------------------------------------------------------------
extern "C" void kernel_launch(void* const* d_in, const int* in_sizes, int n_in,
                              void* d_out, int out_size, void* d_ws, size_t ws_size,
                              hipStream_t stream)
{
    const void* x      = d_in[0];
    const int*  mask   = (const int*)d_in[1];
    const void* wq     = d_in[2];
    const void* bq     = d_in[3];
    const void* wk     = d_in[4];
    const void* bk     = d_in[5];
    const void* wv     = d_in[6];
    const void* bv     = d_in[7];
    const void* wo     = d_in[8];
    const void* bo     = d_in[9];
    const void* w1     = d_in[10];
    const void* b1     = d_in[11];
    const void* w2     = d_in[12];
    const void* b2     = d_in[13];
    const void* alpha1 = d_in[14];
    const void* bias1  = d_in[15];
    const void* alpha2 = d_in[16];
    const void* bias2  = d_in[17];

    char* ws = (char*)d_ws;
    const size_t MB = 1024 * 1024;
    const size_t KB = 1024;
    ushort_t* wqkvT = (ushort_t*)(ws + 0 * MB);   // [3072][1024] bf16
    ushort_t* woT   = (ushort_t*)(ws + 6 * MB);
    ushort_t* w1T   = (ushort_t*)(ws + 8 * MB);
    ushort_t* w2T   = (ushort_t*)(ws + 16 * MB);
    // packed params (floats): see cvt_params
    float* pb    = (float*)(ws + 24 * MB);
    float* bqkvf = pb + 0;
    float* bof   = pb + 3072;
    float* b1f   = pb + 4096;
    float* b2f   = pb + 8192;
    float* a1f   = pb + 9216;
    float* be1f  = pb + 10240;
    float* a2f   = pb + 11264;
    float* be2f  = pb + 12288;
    int*   flag  = (int*)(ws + 24 * MB + 8 * 16 * KB);
    int*   flagz = flag + 1;
    ushort_t* lnbuf = (ushort_t*)(ws + 25 * MB);
    ushort_t* qb    = (ushort_t*)(ws + 41 * MB);
    ushort_t* kb    = (ushort_t*)(ws + 57 * MB);
    ushort_t* vtb   = (ushort_t*)(ws + 73 * MB);
    ushort_t* attnb = lnbuf;

    const bool bigws = (ws_size >= 121ull * MB);

    dim3 blk(256);
    detect_dtype<<<1, 64, 0, stream>>>((const ushort_t*)x, flag);

    cvt_params<<<52, blk, 0, stream>>>(bq, bk, bv, bo, b1, b2,
                                       alpha1, bias1, alpha2, bias2, pb, flag);

    transpose_qkvo<<<dim3(16, 16, 4), blk, 0, stream>>>(wq, wk, wv, wo, wqkvT, flag);
    transpose_to_bf16<<<dim3(64, 16), blk, 0, stream>>>(w1, w1T, D_MODEL, D_FF, 1.f, flag);
    transpose_to_bf16<<<dim3(16, 64), blk, 0, stream>>>(w2, w2T, D_FF, D_MODEL, 1.f, flag);

    ln_kernel<<<M_TOT, blk, 0, stream>>>(x, a1f, be1f, lnbuf, flag);

    gemm_qkv<<<dim3(64, 24), blk, 0, stream>>>(lnbuf, wqkvT, bqkvf, qb, kb, vtb,
                                               M_TOT, D_MODEL);

    attn_kernel<<<dim3(SEQ / 128, BATCH * N_HEADS), blk, 0, stream>>>(qb, kb, vtb, mask, attnb);

    if (bigws) {
        float*    trunk   = (float*)kb;                 // 57-89 MB (32 MB fp32)
        ushort_t* ln2buf  = qb;                         // 41-57
        ushort_t* halfbuf = (ushort_t*)(ws + 89 * MB);  // 89-121 (32 MB bf16)
        gemm_bias_res_trunk<<<dim3(64, 8), blk, 0, stream>>>(attnb, woT, bof, x, trunk,
                                                             M_TOT, D_MODEL, D_MODEL, flag);
        ln_kernel<<<M_TOT, blk, 0, stream>>>(trunk, a2f, be2f, ln2buf, flagz);
        gemm_relu_slice<<<dim3(64, 16), blk, 0, stream>>>(ln2buf, w1T, b1f, halfbuf,
                                                          M_TOT, 2048, D_MODEL, 0);
        gemm_acc_slice<<<dim3(64, 8), blk, 0, stream>>>(halfbuf, w2T, b2f, trunk,
                                                        M_TOT, D_MODEL, 2048, 0, D_FF, 1);
        gemm_relu_slice<<<dim3(64, 16), blk, 0, stream>>>(ln2buf, w1T, b1f, halfbuf,
                                                          M_TOT, 2048, D_MODEL, 2048);
        gemm_acc_final<<<dim3(64, 8), blk, 0, stream>>>(halfbuf, w2T, trunk, d_out,
                                                        M_TOT, D_MODEL, 2048, 2048, D_FF, flag);
    } else {
        float*    trunk   = (float*)qb;    // 41-73 (32 MB fp32), R6-proven
        ushort_t* ln2buf  = vtb;           // 73-89
        ushort_t* halfbuf = lnbuf;         // 25-41 (16 MB)
        gemm_bias_res_trunk<<<dim3(64, 8), blk, 0, stream>>>(attnb, woT, bof, x, trunk,
                                                             M_TOT, D_MODEL, D_MODEL, flag);
        ln_kernel<<<M_TOT, blk, 0, stream>>>(trunk, a2f, be2f, ln2buf, flagz);
        for (int qtr = 0; qtr < 4; qtr++) {
            const int off = qtr * 1024;
            gemm_relu_slice<<<dim3(64, 8), blk, 0, stream>>>(ln2buf, w1T, b1f, halfbuf,
                                                             M_TOT, 1024, D_MODEL, off);
            gemm_acc_slice<<<dim3(64, 8), blk, 0, stream>>>(halfbuf, w2T, b2f, trunk,
                                                            M_TOT, D_MODEL, 1024, off,
                                                            D_FF, qtr == 0 ? 1 : 0);
        }
        finalize_out<<<M_TOT * D_MODEL / 1024, blk, 0, stream>>>(trunk, d_out, flag);
    }
}

// Round 5
// 577.260 us; speedup vs baseline: 1.2000x; 1.2000x over previous
//
#include <hip/hip_runtime.h>

#define D_MODEL 1024
#define D_FF    4096
#define N_HEADS 16
#define DK      64
#define BATCH   4
#define SEQ     2048
#define M_TOT   (BATCH*SEQ)   // 8192

typedef unsigned short ushort_t;
typedef __attribute__((ext_vector_type(8))) short  short8;
typedef __attribute__((ext_vector_type(4))) float  floatx4;

__device__ __forceinline__ float bf2f(ushort_t s) {
    return __uint_as_float(((unsigned int)s) << 16);
}
__device__ __forceinline__ ushort_t f2bf(float f) {
    unsigned int u = __float_as_uint(f);
    u += 0x7fff + ((u >> 16) & 1);   // round-to-nearest-even
    return (ushort_t)(u >> 16);
}
// async global->LDS, 16B per lane; LDS dest = wave-uniform base + lane*16
__device__ __forceinline__ void gll16(const void* g, void* l) {
    __builtin_amdgcn_global_load_lds(
        (const __attribute__((address_space(1))) void*)g,
        (__attribute__((address_space(3))) void*)l,
        16, 0, 0);
}

#if __has_builtin(__builtin_amdgcn_exp2f)
#define EXP2(x) __builtin_amdgcn_exp2f(x)
#else
#define EXP2(x) __expf((x) * 0.69314718055994531f)
#endif
#define L2E 1.4426950408889634f

// ---------------------------------------------------------------------------
// dtype detector (validated R5/R6)
// ---------------------------------------------------------------------------
__global__ void detect_dtype(const ushort_t* __restrict__ x, int* __restrict__ flag)
{
    const int t = threadIdx.x;
    int cnt = 0;
    for (int i = t; i < 512; i += 64) {
        ushort_t e = x[2 * i] & 0x7F80;
        cnt += (e >= 0x3800 && e <= 0x4380) ? 1 : 0;
    }
    for (int off = 32; off > 0; off >>= 1) cnt += __shfl_down(cnt, off, 64);
    if (t == 0) { flag[0] = (cnt >= 256) ? 1 : 0; flag[1] = 0; }
}

// ---------------------------------------------------------------------------
// fused param converter: all 10 small fp32/bf16 vectors -> one packed block.
// packed layout (floats): 0 bqkv(3072, q pre-scaled 1/8) | 3072 bo |
// 4096 b1(4096) | 8192 b2 | 9216 a1 | 10240 be1 | 11264 a2 | 12288 be2
// ---------------------------------------------------------------------------
__global__ void cvt_params(
    const void* bq, const void* bk, const void* bv, const void* bo,
    const void* b1, const void* b2, const void* a1, const void* be1,
    const void* a2, const void* be2, float* __restrict__ dst,
    const int* __restrict__ flag)
{
    const int e = blockIdx.x * 256 + threadIdx.x;   // 0..13311
    const int seg = e >> 10;                        // 0..12
    const void* srcs[13] = {bq, bk, bv, bo, b1, b1, b1, b1, b2, a1, be1, a2, be2};
    const int   base[13] = {0, 1024, 2048, 3072, 4096, 4096, 4096, 4096,
                            8192, 9216, 10240, 11264, 12288};
    const void* s = srcs[seg];
    const int off = e - base[seg];
    const float scale = (seg == 0) ? 0.125f : 1.f;
    float v = (*flag) ? bf2f(((const ushort_t*)s)[off]) : ((const float*)s)[off];
    dst[e] = v * scale;
}

// ---------------------------------------------------------------------------
// weight transpose (+optional scale): in[K][N] -> out[N][K] bf16
// ---------------------------------------------------------------------------
__device__ __forceinline__ void transpose_body(
    const void* __restrict__ in, ushort_t* __restrict__ out, int K, int N,
    float scale, int fl, ushort_t* tile, int n0, int k0)
{
    const int t = threadIdx.x, sr = t >> 2, sc = (t & 3) * 16;
    const long g = (long)(k0 + sr) * N + n0 + sc;
    ushort_t cv[16];
    if (fl) {
        const ushort_t* p = (const ushort_t*)in;
        #pragma unroll
        for (int j = 0; j < 16; j++) cv[j] = f2bf(bf2f(p[g + j]) * scale);
    } else {
        const float* p = (const float*)in;
        #pragma unroll
        for (int j = 0; j < 16; j += 4) {
            float4 fv = *(const float4*)&p[g + j];
            cv[j] = f2bf(fv.x * scale); cv[j+1] = f2bf(fv.y * scale);
            cv[j+2] = f2bf(fv.z * scale); cv[j+3] = f2bf(fv.w * scale);
        }
    }
    #pragma unroll
    for (int j = 0; j < 16; j++) tile[sr * 72 + sc + j] = cv[j];
    __syncthreads();
    __attribute__((aligned(16))) ushort_t tmp[16];
    #pragma unroll
    for (int j = 0; j < 16; j++) tmp[j] = tile[(sc + j) * 72 + sr];
    const long go = (long)(n0 + sr) * K + k0 + sc;
    *(int4*)&out[go]     = *(const int4*)&tmp[0];
    *(int4*)&out[go + 8] = *(const int4*)&tmp[8];
}

__global__ __launch_bounds__(256) void transpose_to_bf16(
    const void* __restrict__ in, ushort_t* __restrict__ out, int K, int N,
    float scale, const int* __restrict__ flag)
{
    __shared__ ushort_t tile[64 * 72];
    transpose_body(in, out, K, N, scale, *flag, tile,
                   blockIdx.x * 64, blockIdx.y * 64);
}

// batched square transpose for wq/wk/wv/wo (dsts contiguous in ws)
__global__ __launch_bounds__(256) void transpose_qkvo(
    const void* __restrict__ wq, const void* __restrict__ wk,
    const void* __restrict__ wv, const void* __restrict__ wo,
    ushort_t* __restrict__ out, const int* __restrict__ flag)
{
    __shared__ ushort_t tile[64 * 72];
    const int z = blockIdx.z;
    const void* in = (z == 0) ? wq : (z == 1) ? wk : (z == 2) ? wv : wo;
    transpose_body(in, out + (long)z * 1024 * 1024, 1024, 1024,
                   (z == 0) ? 0.125f : 1.f, *flag, tile,
                   blockIdx.x * 64, blockIdx.y * 64);
}

// ---------------------------------------------------------------------------
// Tensor1DNorm (validated)
// ---------------------------------------------------------------------------
__global__ __launch_bounds__(256) void ln_kernel(
    const void* __restrict__ xraw, const float* __restrict__ alpha,
    const float* __restrict__ beta, ushort_t* __restrict__ out,
    const int* __restrict__ flag)
{
    __shared__ float red[8];
    __shared__ float stats[2];
    const int row = blockIdx.x, t = threadIdx.x;
    const long idx = (long)row * D_MODEL + t * 4;
    float v0, v1, v2, v3;
    if (*flag) {
        ushort4 u = *(const ushort4*)&((const ushort_t*)xraw)[idx];
        v0 = bf2f(u.x); v1 = bf2f(u.y); v2 = bf2f(u.z); v3 = bf2f(u.w);
    } else {
        float4 fv = *(const float4*)&((const float*)xraw)[idx];
        v0 = fv.x; v1 = fv.y; v2 = fv.z; v3 = fv.w;
    }
    float s  = v0 + v1 + v2 + v3;
    float s2 = v0 * v0 + v1 * v1 + v2 * v2 + v3 * v3;
    for (int off = 32; off > 0; off >>= 1) {
        s  += __shfl_down(s,  off, 64);
        s2 += __shfl_down(s2, off, 64);
    }
    const int w = t >> 6, lane = t & 63;
    if (lane == 0) { red[w] = s; red[4 + w] = s2; }
    __syncthreads();
    if (t == 0) {
        float S  = red[0] + red[1] + red[2] + red[3];
        float S2 = red[4] + red[5] + red[6] + red[7];
        float mean = S / D_MODEL;
        float var  = fmaxf((S2 - mean * S) / (D_MODEL - 1), 0.f);
        stats[0] = mean;
        stats[1] = 1.f / (sqrtf(var) + 1e-6f);
    }
    __syncthreads();
    const float mean = stats[0], inv = stats[1];
    float vv[4] = {v0, v1, v2, v3};
    ushort4 o;
    ushort_t* op = (ushort_t*)&o;
    #pragma unroll
    for (int j = 0; j < 4; j++)
        op[j] = f2bf(alpha[t * 4 + j] * (vv[j] - mean) * inv + beta[t * 4 + j]);
    *(ushort4*)&out[idx] = o;
}

// ---------------------------------------------------------------------------
// GEMM core (R3-validated, reverted from R4): 128x128 tile, BK=64,
// 16x16x32 MFMA, gll16 staging with G4 XOR swizzle.
// LDS[row][c] holds global[row][c ^ (row&7)*8]; staged via pre-swizzled
// global source (linear LDS dest, rule 21c); ds_read applies the same XOR.
// ---------------------------------------------------------------------------
#define GEMM_PROLOG()                                                         \
    __shared__ ushort_t As[128 * 64];                                         \
    __shared__ ushort_t Bs[128 * 64];                                         \
    const int m0 = blockIdx.x * 128, n0 = blockIdx.y * 128;                   \
    const int t = threadIdx.x;                                                \
    const int w = t >> 6, lane = t & 63, quad = lane >> 4, l15 = lane & 15;   \
    const int wm = (w >> 1) * 64, wn = (w & 1) * 64;                          \
    const int srow = lane >> 3;                    /* staging row-in-8 */     \
    const int scol = 8 * ((lane & 7) ^ (srow & 7)); /* pre-swizzled col */    \
    const int rswz = (l15 & 7) * 8;                /* read-side XOR */        \
    floatx4 acc[4][4] = {};

#define GEMM_KLOOP(Abase, LDA, Bbase, LDB, KLEN)                              \
    {                                                                         \
    const ushort_t* gA = (Abase) + (long)(m0 + w * 32 + srow) * (LDA) + scol; \
    const ushort_t* gB = (Bbase) + (long)(n0 + w * 32 + srow) * (LDB) + scol; \
    for (int k0 = 0; k0 < (KLEN); k0 += 64) {                                 \
        _Pragma("unroll")                                                     \
        for (int c = 0; c < 4; c++) {                                         \
            gll16(gA + k0 + (long)(c * 8) * (LDA), &As[(w * 32 + c * 8) * 64]);\
            gll16(gB + k0 + (long)(c * 8) * (LDB), &Bs[(w * 32 + c * 8) * 64]);\
        }                                                                     \
        __syncthreads();                                                      \
        _Pragma("unroll")                                                     \
        for (int kk = 0; kk < 2; kk++) {                                      \
            short8 af[4], bf[4];                                              \
            _Pragma("unroll")                                                 \
            for (int i = 0; i < 4; i++)                                       \
                af[i] = *(const short8*)&As[(wm + i * 16 + l15) * 64 +        \
                        ((kk * 32 + quad * 8) ^ rswz)];                       \
            _Pragma("unroll")                                                 \
            for (int j = 0; j < 4; j++)                                       \
                bf[j] = *(const short8*)&Bs[(wn + j * 16 + l15) * 64 +        \
                        ((kk * 32 + quad * 8) ^ rswz)];                       \
            _Pragma("unroll")                                                 \
            for (int i = 0; i < 4; i++) {                                     \
                _Pragma("unroll")                                             \
                for (int j = 0; j < 4; j++)                                   \
                    acc[i][j] = __builtin_amdgcn_mfma_f32_16x16x32_bf16(      \
                        af[i], bf[j], acc[i][j], 0, 0, 0);                    \
            }                                                                 \
        }                                                                     \
        __syncthreads();                                                      \
    }                                                                         \
    }

// Fused QKV: BT = wqkvT [3072][1024]; epilogue routes per 1024-segment.
// seg0 -> qb [M][1024]; seg1 -> kb; seg2 -> vt [B][H][DK][S].
__global__ __launch_bounds__(256) void gemm_qkv(
    const ushort_t* __restrict__ A, const ushort_t* __restrict__ BT,
    const float* __restrict__ bias, ushort_t* __restrict__ qb,
    ushort_t* __restrict__ kb, ushort_t* __restrict__ vtb, int M, int K)
{
    GEMM_PROLOG();
    GEMM_KLOOP(A, K, BT, K, K);
    const int nbase = n0 + wn;          // multiple of 64; wave-uniform segment
    const int seg = nbase >> 10;
    #pragma unroll
    for (int j = 0; j < 4; j++) {
        const int ng = nbase + j * 16 + l15;
        const float bv = bias[ng];
        const int nl = ng & 1023;
        #pragma unroll
        for (int i = 0; i < 4; i++) {
            const int mb_ = m0 + wm + i * 16 + quad * 4;
            if (seg == 2) {
                ushort4 pv;
                #pragma unroll
                for (int r = 0; r < 4; r++)
                    ((ushort_t*)&pv)[r] = f2bf(acc[i][j][r] + bv);
                const long idx = ((long)(mb_ >> 11) * 1024 + nl) * 2048 + (mb_ & 2047);
                *(ushort4*)&vtb[idx] = pv;
            } else {
                ushort_t* dst = seg ? kb : qb;
                #pragma unroll
                for (int r = 0; r < 4; r++)
                    dst[(long)(mb_ + r) * 1024 + nl] = f2bf(acc[i][j][r] + bv);
            }
        }
    }
}

// O-proj: trunk fp32 = A @ BT^T + bias + raw-x residual (flag-typed)
__global__ __launch_bounds__(256) void gemm_bias_res_trunk(
    const ushort_t* __restrict__ A, const ushort_t* __restrict__ BT,
    const float* __restrict__ bias, const void* __restrict__ res,
    float* __restrict__ C, int M, int N, int K, const int* __restrict__ flag)
{
    GEMM_PROLOG();
    const int fl = *flag;
    GEMM_KLOOP(A, K, BT, K, K);
    #pragma unroll
    for (int j = 0; j < 4; j++) {
        const int n = n0 + wn + j * 16 + l15;
        const float bv = bias[n];
        #pragma unroll
        for (int i = 0; i < 4; i++) {
            const int mbase = m0 + wm + i * 16 + quad * 4;
            #pragma unroll
            for (int r = 0; r < 4; r++) {
                const long idx = (long)(mbase + r) * N + n;
                const float rv = fl ? bf2f(((const ushort_t*)res)[idx])
                                    : ((const float*)res)[idx];
                C[idx] = acc[i][j][r] + bv + rv;
            }
        }
    }
}

// FF1 slice: C[M][Nc] bf16 = relu(A @ BT[noff..]^T + bias[noff..])
__global__ __launch_bounds__(256) void gemm_relu_slice(
    const ushort_t* __restrict__ A, const ushort_t* __restrict__ BT,
    const float* __restrict__ bias, ushort_t* __restrict__ C,
    int M, int Nc, int K, int noff)
{
    GEMM_PROLOG();
    const ushort_t* BTo = BT + (long)noff * K;
    GEMM_KLOOP(A, K, BTo, K, K);
    #pragma unroll
    for (int j = 0; j < 4; j++) {
        const int n = n0 + wn + j * 16 + l15;
        const float bv = bias[noff + n];
        #pragma unroll
        for (int i = 0; i < 4; i++) {
            const int mbase = m0 + wm + i * 16 + quad * 4;
            #pragma unroll
            for (int r = 0; r < 4; r++)
                C[(long)(mbase + r) * Nc + n] = f2bf(fmaxf(acc[i][j][r] + bv, 0.f));
        }
    }
}

// FF2 slice accumulate into fp32 trunk (pass0: += bias; trunk holds residual)
__global__ __launch_bounds__(256) void gemm_acc_slice(
    const ushort_t* __restrict__ A, const ushort_t* __restrict__ BT,
    const float* __restrict__ bias, float* __restrict__ C,
    int M, int N, int Kc, int koff, int Kfull, int pass0)
{
    GEMM_PROLOG();
    const ushort_t* BTo = BT + koff;
    GEMM_KLOOP(A, Kc, BTo, Kfull, Kc);
    #pragma unroll
    for (int j = 0; j < 4; j++) {
        const int n = n0 + wn + j * 16 + l15;
        const float bv = pass0 ? bias[n] : 0.f;
        #pragma unroll
        for (int i = 0; i < 4; i++) {
            const int mbase = m0 + wm + i * 16 + quad * 4;
            #pragma unroll
            for (int r = 0; r < 4; r++) {
                const long idx = (long)(mbase + r) * N + n;
                C[idx] = C[idx] + bv + acc[i][j][r];
            }
        }
    }
}

// FF2 final slice: out (per flag dtype) = Cin + A @ BTslice^T
__global__ __launch_bounds__(256) void gemm_acc_final(
    const ushort_t* __restrict__ A, const ushort_t* __restrict__ BT,
    const float* __restrict__ Cin, void* __restrict__ out,
    int M, int N, int Kc, int koff, int Kfull, const int* __restrict__ flag)
{
    GEMM_PROLOG();
    const int fl = *flag;
    const ushort_t* BTo = BT + koff;
    GEMM_KLOOP(A, Kc, BTo, Kfull, Kc);
    #pragma unroll
    for (int j = 0; j < 4; j++) {
        const int n = n0 + wn + j * 16 + l15;
        #pragma unroll
        for (int i = 0; i < 4; i++) {
            const int mbase = m0 + wm + i * 16 + quad * 4;
            #pragma unroll
            for (int r = 0; r < 4; r++) {
                const long idx = (long)(mbase + r) * N + n;
                const float v = Cin[idx] + acc[i][j][r];
                if (fl) ((ushort_t*)out)[idx] = f2bf(v);
                else    ((float*)out)[idx] = v;
            }
        }
    }
}

__global__ __launch_bounds__(256) void finalize_out(
    const float* __restrict__ trunk, void* __restrict__ out,
    const int* __restrict__ flag)
{
    const long i = ((long)blockIdx.x * 256 + threadIdx.x) * 4;
    float4 tv = *(const float4*)&trunk[i];
    if (*flag) {
        ushort4 o = { f2bf(tv.x), f2bf(tv.y), f2bf(tv.z), f2bf(tv.w) };
        *(ushort4*)&((ushort_t*)out)[i] = o;
    } else {
        *(float4*)&((float*)out)[i] = tv;
    }
}

// ---------------------------------------------------------------------------
// Flash attention v5 (R2-validated): QBLK=128, fixed-max softmax, ones-MFMA
// row-sum, reg-prefetch staging, Q hoisted, Ps aliases Q staging region.
// ---------------------------------------------------------------------------
__global__ __launch_bounds__(256) void attn_kernel(
    const ushort_t* __restrict__ q, const ushort_t* __restrict__ k,
    const ushort_t* __restrict__ vt, const int* __restrict__ mask,
    ushort_t* __restrict__ out)
{
    __shared__ ushort_t Ks[64 * 72];
    __shared__ ushort_t Vs[64 * 72];
    __shared__ ushort_t Ps[128 * 72];   // Q staging first, then P tile
    __shared__ float MbL[64];
    const int qt = blockIdx.x, bh = blockIdx.y;
    const int b = bh >> 4, h = bh & 15;
    const int t = threadIdx.x, w = t >> 6, lane = t & 63;
    const int quad = lane >> 4, l15 = lane & 15;
    const int sr = t >> 2, sc = (t & 3) * 16;
    const int q0 = qt * 128;
    const long rowbase = (long)b * SEQ * D_MODEL + (long)h * DK;
    const long vtbase  = ((long)(b * 16 + h) * DK) * SEQ;

    // ---- stage Q 128x64 (wave-private rows: wave w stages rows 32w..32w+31)
    {
        const int qr = t >> 1, qc = (t & 1) * 32;
        const long g = rowbase + (long)(q0 + qr) * D_MODEL + qc;
        *(int4*)&Ps[qr * 72 + qc]      = *(const int4*)&q[g];
        *(int4*)&Ps[qr * 72 + qc + 8]  = *(const int4*)&q[g + 8];
        *(int4*)&Ps[qr * 72 + qc + 16] = *(const int4*)&q[g + 16];
        *(int4*)&Ps[qr * 72 + qc + 24] = *(const int4*)&q[g + 24];
    }
    // hoist loop-invariant Q fragments (same-wave LDS: no barrier needed)
    short8 bq[2][2];
    #pragma unroll
    for (int qg = 0; qg < 2; qg++)
        #pragma unroll
        for (int ks = 0; ks < 2; ks++)
            bq[qg][ks] = *(const short8*)&Ps[(w * 32 + qg * 16 + l15) * 72 + ks * 32 + quad * 8];

    short8 bones;
    #pragma unroll
    for (int i = 0; i < 8; i++) bones[i] = (short)0x3F80;   // bf16 1.0

    floatx4 o[2][4] = {};
    floatx4 l4[2] = {};    // row-sum accumulators (P·1)

    // ---- prefetch K/V tile 0 + mask into registers
    int4 kra, krb, vra, vrb;
    int  mreg = 0;
    {
        const long gk = rowbase + (long)sr * D_MODEL + sc;
        kra = *(const int4*)&k[gk]; krb = *(const int4*)&k[gk + 8];
        const long gv = vtbase + (long)sr * SEQ + sc;
        vra = *(const int4*)&vt[gv]; vrb = *(const int4*)&vt[gv + 8];
        if (t < 64) mreg = mask[b * SEQ + t];
    }

    for (int kt = 0; kt < SEQ / 64; kt++) {
        __syncthreads();     // previous iteration's readers done
        *(int4*)&Ks[sr * 72 + sc]     = kra;
        *(int4*)&Ks[sr * 72 + sc + 8] = krb;
        *(int4*)&Vs[sr * 72 + sc]     = vra;
        *(int4*)&Vs[sr * 72 + sc + 8] = vrb;
        if (t < 64) MbL[t] = (mreg == 0) ? -1.0e9f : -44.0f;
        __syncthreads();
        if (kt + 1 < SEQ / 64) {   // issue next-tile loads; compute hides them
            const long gk = rowbase + (long)((kt + 1) * 64 + sr) * D_MODEL + sc;
            kra = *(const int4*)&k[gk]; krb = *(const int4*)&k[gk + 8];
            const long gv = vtbase + (long)sr * SEQ + (kt + 1) * 64 + sc;
            vra = *(const int4*)&vt[gv]; vrb = *(const int4*)&vt[gv + 8];
            if (t < 64) mreg = mask[b * SEQ + (kt + 1) * 64 + t];
        }

        // S^T = K·Q^T  (q pre-scaled by 1/8); each ak feeds 2 q-groups
        floatx4 s[4][2] = {};
        __builtin_amdgcn_s_setprio(1);
        #pragma unroll
        for (int nt = 0; nt < 4; nt++) {
            short8 ak0 = *(const short8*)&Ks[(nt * 16 + l15) * 72 + quad * 8];
            s[nt][0] = __builtin_amdgcn_mfma_f32_16x16x32_bf16(ak0, bq[0][0], s[nt][0], 0, 0, 0);
            s[nt][1] = __builtin_amdgcn_mfma_f32_16x16x32_bf16(ak0, bq[1][0], s[nt][1], 0, 0, 0);
            short8 ak1 = *(const short8*)&Ks[(nt * 16 + l15) * 72 + 32 + quad * 8];
            s[nt][0] = __builtin_amdgcn_mfma_f32_16x16x32_bf16(ak1, bq[0][1], s[nt][0], 0, 0, 0);
            s[nt][1] = __builtin_amdgcn_mfma_f32_16x16x32_bf16(ak1, bq[1][1], s[nt][1], 0, 0, 0);
        }
        __builtin_amdgcn_s_setprio(0);

        // p = exp2(s*L2E - 44); masked cols -> -1e9 -> exactly 0.
        // P packed to bf16 by truncation via v_perm (2 values/op).
        #pragma unroll
        for (int qg = 0; qg < 2; qg++) {
            #pragma unroll
            for (int nt = 0; nt < 4; nt++) {
                float4 mb4 = *(const float4*)&MbL[nt * 16 + quad * 4];
                float p[4];
                #pragma unroll
                for (int r = 0; r < 4; r++)
                    p[r] = EXP2(fmaf(s[nt][qg][r], L2E, ((const float*)&mb4)[r]));
                uint2 pk;
                pk.x = __builtin_amdgcn_perm(__float_as_uint(p[1]), __float_as_uint(p[0]), 0x07060302u);
                pk.y = __builtin_amdgcn_perm(__float_as_uint(p[3]), __float_as_uint(p[2]), 0x07060302u);
                *(uint2*)&Ps[(w * 32 + qg * 16 + l15) * 72 + nt * 16 + quad * 4] = pk;
            }
        }

        // O += P·V ; l4 += P·1  (Ps rows wave-private: no barrier needed);
        // each bv feeds 2 q-groups.
        __builtin_amdgcn_s_setprio(1);
        #pragma unroll
        for (int ks = 0; ks < 2; ks++) {
            short8 ap0 = *(const short8*)&Ps[(w * 32 + l15) * 72 + ks * 32 + quad * 8];
            short8 ap1 = *(const short8*)&Ps[(w * 32 + 16 + l15) * 72 + ks * 32 + quad * 8];
            #pragma unroll
            for (int j = 0; j < 4; j++) {
                short8 bv = *(const short8*)&Vs[(j * 16 + l15) * 72 + ks * 32 + quad * 8];
                o[0][j] = __builtin_amdgcn_mfma_f32_16x16x32_bf16(ap0, bv, o[0][j], 0, 0, 0);
                o[1][j] = __builtin_amdgcn_mfma_f32_16x16x32_bf16(ap1, bv, o[1][j], 0, 0, 0);
            }
            l4[0] = __builtin_amdgcn_mfma_f32_16x16x32_bf16(ap0, bones, l4[0], 0, 0, 0);
            l4[1] = __builtin_amdgcn_mfma_f32_16x16x32_bf16(ap1, bones, l4[1], 0, 0, 0);
        }
        __builtin_amdgcn_s_setprio(0);
    }
    // l4[qg][r] = row-sum for q-row (w*32 + qg*16 + quad*4 + r)
    #pragma unroll
    for (int qg = 0; qg < 2; qg++) {
        float inv[4];
        #pragma unroll
        for (int r = 0; r < 4; r++) inv[r] = 1.f / l4[qg][r];
        #pragma unroll
        for (int j = 0; j < 4; j++) {
            const int d = j * 16 + l15;
            #pragma unroll
            for (int r = 0; r < 4; r++) {
                const int row = q0 + w * 32 + qg * 16 + quad * 4 + r;
                out[rowbase + (long)row * D_MODEL + d] = f2bf(o[qg][j][r] * inv[r]);
            }
        }
    }
}

// ---------------------------------------------------------------------------
// Launch. Common: 0-6 wqkvT, 6-8 woT, 8-16 w1T, 16-24 w2T, 24-25 params,
// 25-41 lnbuf/attnb, 41-57 qb, 57-73 kb, 73-89 vtb.
// Path A (ws>=121MB): trunk fp32 57-89, ln2buf 41-57, halfbuf 89-121.
// Path A' (fp32 out): same but halfbuf = d_out (32MB), finalize at end.
// Path B (fallback):  R6-proven quarters (trunk 41-73, ln2buf 73-89,
//                     halfbuf 25-41).
// ---------------------------------------------------------------------------
extern "C" void kernel_launch(void* const* d_in, const int* in_sizes, int n_in,
                              void* d_out, int out_size, void* d_ws, size_t ws_size,
                              hipStream_t stream)
{
    const void* x      = d_in[0];
    const int*  mask   = (const int*)d_in[1];
    const void* wq     = d_in[2];
    const void* bq     = d_in[3];
    const void* wk     = d_in[4];
    const void* bk     = d_in[5];
    const void* wv     = d_in[6];
    const void* bv     = d_in[7];
    const void* wo     = d_in[8];
    const void* bo     = d_in[9];
    const void* w1     = d_in[10];
    const void* b1     = d_in[11];
    const void* w2     = d_in[12];
    const void* b2     = d_in[13];
    const void* alpha1 = d_in[14];
    const void* bias1  = d_in[15];
    const void* alpha2 = d_in[16];
    const void* bias2  = d_in[17];

    char* ws = (char*)d_ws;
    const size_t MB = 1024 * 1024;
    const size_t KB = 1024;
    ushort_t* wqkvT = (ushort_t*)(ws + 0 * MB);   // [3072][1024] bf16
    ushort_t* woT   = (ushort_t*)(ws + 6 * MB);
    ushort_t* w1T   = (ushort_t*)(ws + 8 * MB);
    ushort_t* w2T   = (ushort_t*)(ws + 16 * MB);
    // packed params (floats): see cvt_params
    float* pb    = (float*)(ws + 24 * MB);
    float* bqkvf = pb + 0;
    float* bof   = pb + 3072;
    float* b1f   = pb + 4096;
    float* b2f   = pb + 8192;
    float* a1f   = pb + 9216;
    float* be1f  = pb + 10240;
    float* a2f   = pb + 11264;
    float* be2f  = pb + 12288;
    int*   flag  = (int*)(ws + 24 * MB + 8 * 16 * KB);
    int*   flagz = flag + 1;
    ushort_t* lnbuf = (ushort_t*)(ws + 25 * MB);
    ushort_t* qb    = (ushort_t*)(ws + 41 * MB);
    ushort_t* kb    = (ushort_t*)(ws + 57 * MB);
    ushort_t* vtb   = (ushort_t*)(ws + 73 * MB);
    ushort_t* attnb = lnbuf;

    const bool bigws   = (ws_size >= 121ull * MB);
    const bool outf32  = (out_size == (int)(sizeof(float) * M_TOT * D_MODEL));

    dim3 blk(256);
    detect_dtype<<<1, 64, 0, stream>>>((const ushort_t*)x, flag);

    cvt_params<<<52, blk, 0, stream>>>(bq, bk, bv, bo, b1, b2,
                                       alpha1, bias1, alpha2, bias2, pb, flag);

    transpose_qkvo<<<dim3(16, 16, 4), blk, 0, stream>>>(wq, wk, wv, wo, wqkvT, flag);
    transpose_to_bf16<<<dim3(64, 16), blk, 0, stream>>>(w1, w1T, D_MODEL, D_FF, 1.f, flag);
    transpose_to_bf16<<<dim3(16, 64), blk, 0, stream>>>(w2, w2T, D_FF, D_MODEL, 1.f, flag);

    ln_kernel<<<M_TOT, blk, 0, stream>>>(x, a1f, be1f, lnbuf, flag);

    gemm_qkv<<<dim3(64, 24), blk, 0, stream>>>(lnbuf, wqkvT, bqkvf, qb, kb, vtb,
                                               M_TOT, D_MODEL);

    attn_kernel<<<dim3(SEQ / 128, BATCH * N_HEADS), blk, 0, stream>>>(qb, kb, vtb, mask, attnb);

    if (bigws) {
        float*    trunk   = (float*)kb;                 // 57-89 MB (32 MB fp32)
        ushort_t* ln2buf  = qb;                         // 41-57
        ushort_t* halfbuf = (ushort_t*)(ws + 89 * MB);  // 89-121 (32 MB bf16)
        gemm_bias_res_trunk<<<dim3(64, 8), blk, 0, stream>>>(attnb, woT, bof, x, trunk,
                                                             M_TOT, D_MODEL, D_MODEL, flag);
        ln_kernel<<<M_TOT, blk, 0, stream>>>(trunk, a2f, be2f, ln2buf, flagz);
        gemm_relu_slice<<<dim3(64, 16), blk, 0, stream>>>(ln2buf, w1T, b1f, halfbuf,
                                                          M_TOT, 2048, D_MODEL, 0);
        gemm_acc_slice<<<dim3(64, 8), blk, 0, stream>>>(halfbuf, w2T, b2f, trunk,
                                                        M_TOT, D_MODEL, 2048, 0, D_FF, 1);
        gemm_relu_slice<<<dim3(64, 16), blk, 0, stream>>>(ln2buf, w1T, b1f, halfbuf,
                                                          M_TOT, 2048, D_MODEL, 2048);
        gemm_acc_final<<<dim3(64, 8), blk, 0, stream>>>(halfbuf, w2T, trunk, d_out,
                                                        M_TOT, D_MODEL, 2048, 2048, D_FF, flag);
    } else if (outf32) {
        // small ws but fp32 output: d_out (32 MB) serves as the half-buffer.
        float*    trunk   = (float*)kb;        // 57-89 (kb+vtb free after attn)
        ushort_t* ln2buf  = qb;                // 41-57
        ushort_t* halfbuf = (ushort_t*)d_out;  // 32 MB scratch until finalize
        gemm_bias_res_trunk<<<dim3(64, 8), blk, 0, stream>>>(attnb, woT, bof, x, trunk,
                                                             M_TOT, D_MODEL, D_MODEL, flag);
        ln_kernel<<<M_TOT, blk, 0, stream>>>(trunk, a2f, be2f, ln2buf, flagz);
        gemm_relu_slice<<<dim3(64, 16), blk, 0, stream>>>(ln2buf, w1T, b1f, halfbuf,
                                                          M_TOT, 2048, D_MODEL, 0);
        gemm_acc_slice<<<dim3(64, 8), blk, 0, stream>>>(halfbuf, w2T, b2f, trunk,
                                                        M_TOT, D_MODEL, 2048, 0, D_FF, 1);
        gemm_relu_slice<<<dim3(64, 16), blk, 0, stream>>>(ln2buf, w1T, b1f, halfbuf,
                                                          M_TOT, 2048, D_MODEL, 2048);
        gemm_acc_slice<<<dim3(64, 8), blk, 0, stream>>>(halfbuf, w2T, b2f, trunk,
                                                        M_TOT, D_MODEL, 2048, 2048, D_FF, 0);
        finalize_out<<<M_TOT * D_MODEL / 1024, blk, 0, stream>>>(trunk, d_out, flag);
    } else {
        float*    trunk   = (float*)qb;    // 41-73 (32 MB fp32), R6-proven
        ushort_t* ln2buf  = vtb;           // 73-89
        ushort_t* halfbuf = lnbuf;         // 25-41 (16 MB)
        gemm_bias_res_trunk<<<dim3(64, 8), blk, 0, stream>>>(attnb, woT, bof, x, trunk,
                                                             M_TOT, D_MODEL, D_MODEL, flag);
        ln_kernel<<<M_TOT, blk, 0, stream>>>(trunk, a2f, be2f, ln2buf, flagz);
        for (int qtr = 0; qtr < 4; qtr++) {
            const int off = qtr * 1024;
            gemm_relu_slice<<<dim3(64, 8), blk, 0, stream>>>(ln2buf, w1T, b1f, halfbuf,
                                                             M_TOT, 1024, D_MODEL, off);
            gemm_acc_slice<<<dim3(64, 8), blk, 0, stream>>>(halfbuf, w2T, b2f, trunk,
                                                            M_TOT, D_MODEL, 1024, off,
                                                            D_FF, qtr == 0 ? 1 : 0);
        }
        finalize_out<<<M_TOT * D_MODEL / 1024, blk, 0, stream>>>(trunk, d_out, flag);
    }
}